// Round 1
// 329.142 us; speedup vs baseline: 1.0158x; 1.0158x over previous
//
#include <hip/hip_runtime.h>
#include <math.h>

// SlotAttention: B=32, T=4096, D=512
//   scores[b,t] = <inp[b,t,:], slot[:]>; mask t>=lens[b]; softmax over t;
//   context[b,d] = sum_t w[b,t]*inp[b,t,d]
//
// Fused online-softmax single pass over inp (reads each valid row exactly once).
// R2: ping-pong register double-buffer (no a<-n copies), packed (m,l) float2
// records, wave-parallel combine reduction + unrolled c_arr accumulation.

#define BB 32
#define TT 4096
#define DD 512

__global__ __launch_bounds__(256) void
slot_partial_kernel(const float* __restrict__ inp,
                    const int* __restrict__ lens,
                    const float* __restrict__ slot,
                    float2* __restrict__ ml_arr,
                    float* __restrict__ c_arr,
                    int CH, int R, int RW) {
    const int chunk = blockIdx.x;
    const int b     = blockIdx.y;
    const int tid   = threadIdx.x;
    const int wave  = tid >> 6;
    const int lane  = tid & 63;
    const int p     = b * CH + chunk;

    const int len = lens[b];
    const int cs  = chunk * R;
    const int ws_start = cs + wave * RW;
    const int ws_end   = min(ws_start + RW, len);   // may be <= ws_start

    // slot fragment: lane covers d = lane*4..+3 and 256+lane*4..+3
    const float4 s0 = *reinterpret_cast<const float4*>(slot + lane * 4);
    const float4 s1 = *reinterpret_cast<const float4*>(slot + 256 + lane * 4);

    float  m = -INFINITY;
    float  l = 0.0f;
    float4 c0 = make_float4(0.f, 0.f, 0.f, 0.f);
    float4 c1 = make_float4(0.f, 0.f, 0.f, 0.f);

    const float* bp = inp + (size_t)b * TT * DD;

    if (ws_start < ws_end) {
        float4 bufA[4][2], bufB[4][2];

        auto LOAD = [&](float4 (&buf)[4][2], int g) {
            #pragma unroll
            for (int r = 0; r < 4; ++r) {
                const int t = min(g + r, ws_end - 1);   // clamped rows get weight 0
                const float* rp = bp + (size_t)t * DD + lane * 4;
                buf[r][0] = *reinterpret_cast<const float4*>(rp);
                buf[r][1] = *reinterpret_cast<const float4*>(rp + 256);
            }
        };

        auto PROC = [&](float4 (&buf)[4][2], int g) {
            // 4 partial dots
            float sd[4];
            #pragma unroll
            for (int r = 0; r < 4; ++r) {
                sd[r] = buf[r][0].x * s0.x + buf[r][0].y * s0.y
                      + buf[r][0].z * s0.z + buf[r][0].w * s0.w
                      + buf[r][1].x * s1.x + buf[r][1].y * s1.y
                      + buf[r][1].z * s1.z + buf[r][1].w * s1.w;
            }
            // 4 interleaved butterfly reduces (independent chains)
            #pragma unroll
            for (int off = 32; off >= 1; off >>= 1) {
                #pragma unroll
                for (int r = 0; r < 4; ++r)
                    sd[r] += __shfl_xor(sd[r], off, 64);
            }
            // mask tail rows
            #pragma unroll
            for (int r = 0; r < 4; ++r)
                if (g + r >= ws_end) sd[r] = -INFINITY;

            const float gmax = fmaxf(fmaxf(sd[0], sd[1]), fmaxf(sd[2], sd[3]));
            if (gmax > m) {                       // wave-uniform, rare
                const float alpha = __expf(m - gmax);   // first time: 0
                l *= alpha;
                c0.x *= alpha; c0.y *= alpha; c0.z *= alpha; c0.w *= alpha;
                c1.x *= alpha; c1.y *= alpha; c1.z *= alpha; c1.w *= alpha;
                m = gmax;
            }
            #pragma unroll
            for (int r = 0; r < 4; ++r) {
                const float w = __expf(sd[r] - m);   // -inf rows -> 0
                l += w;
                c0.x += w * buf[r][0].x; c0.y += w * buf[r][0].y;
                c0.z += w * buf[r][0].z; c0.w += w * buf[r][0].w;
                c1.x += w * buf[r][1].x; c1.y += w * buf[r][1].y;
                c1.z += w * buf[r][1].z; c1.w += w * buf[r][1].w;
            }
        };

        // ping-pong double-buffer: each group loaded once, no register copies
        int g = ws_start;
        LOAD(bufA, g);
        while (true) {
            int gn = g + 4;
            if (gn < ws_end) LOAD(bufB, gn);
            PROC(bufA, g);
            if (gn >= ws_end) break;
            g = gn;

            gn = g + 4;
            if (gn < ws_end) LOAD(bufA, gn);
            PROC(bufB, g);
            if (gn >= ws_end) break;
            g = gn;
        }
    }

    // combine the block's 4 waves in LDS
    __shared__ float sm[4];
    __shared__ float sl[4];
    __shared__ float sc[4][DD];

    if (lane == 0) { sm[wave] = m; sl[wave] = l; }
    *reinterpret_cast<float4*>(&sc[wave][lane * 4])       = c0;
    *reinterpret_cast<float4*>(&sc[wave][256 + lane * 4]) = c1;
    __syncthreads();

    const float M = fmaxf(fmaxf(sm[0], sm[1]), fmaxf(sm[2], sm[3]));
    float aw[4];
    float L = 0.0f;
    #pragma unroll
    for (int w = 0; w < 4; ++w) {
        aw[w] = (sm[w] == -INFINITY) ? 0.0f : __expf(sm[w] - M);
        L += sl[w] * aw[w];
    }

    // 256 threads x float2 covers D=512
    {
        const int d = tid * 2;
        float2 acc;
        acc.x = sc[0][d]     * aw[0] + sc[1][d]     * aw[1]
              + sc[2][d]     * aw[2] + sc[3][d]     * aw[3];
        acc.y = sc[0][d + 1] * aw[0] + sc[1][d + 1] * aw[1]
              + sc[2][d + 1] * aw[2] + sc[3][d + 1] * aw[3];
        *reinterpret_cast<float2*>(c_arr + (size_t)p * DD + d) = acc;
    }
    if (tid == 0) ml_arr[p] = make_float2(M, L);
}

__global__ __launch_bounds__(256) void
slot_combine_kernel(const float2* __restrict__ ml_arr,
                    const float* __restrict__ c_arr,
                    float* __restrict__ out,
                    int CH) {
    const int b   = blockIdx.x;
    const int tid = threadIdx.x;

    __shared__ float sAlpha[64];
    __shared__ float sInvL;

    // wave 0 does the chunk reduction (CH <= 64 always here)
    if (tid < 64) {
        float mj = -INFINITY, lj = 0.0f;
        if (tid < CH) {
            const float2 v = ml_arr[b * CH + tid];
            mj = v.x; lj = v.y;
        }
        float M = mj;
        #pragma unroll
        for (int off = 32; off >= 1; off >>= 1)
            M = fmaxf(M, __shfl_xor(M, off, 64));
        const float a = (mj == -INFINITY) ? 0.0f : __expf(mj - M);
        float Lp = lj * a;
        #pragma unroll
        for (int off = 32; off >= 1; off >>= 1)
            Lp += __shfl_xor(Lp, off, 64);
        sAlpha[tid] = a;
        if (tid == 0) sInvL = 1.0f / Lp;   // lens[b] >= 1 => Lp > 0
    }
    __syncthreads();

    const float invL = sInvL;
    const int d = tid * 2;
    const float* cb = c_arr + (size_t)b * CH * DD + d;

    // 4 independent accumulator pairs pipeline the loads
    float2 a0 = make_float2(0.f, 0.f), a1 = make_float2(0.f, 0.f);
    float2 a2 = make_float2(0.f, 0.f), a3 = make_float2(0.f, 0.f);
    int j = 0;
    for (; j + 4 <= CH; j += 4) {
        const float2 v0 = *reinterpret_cast<const float2*>(cb + (size_t)(j + 0) * DD);
        const float2 v1 = *reinterpret_cast<const float2*>(cb + (size_t)(j + 1) * DD);
        const float2 v2 = *reinterpret_cast<const float2*>(cb + (size_t)(j + 2) * DD);
        const float2 v3 = *reinterpret_cast<const float2*>(cb + (size_t)(j + 3) * DD);
        a0.x += v0.x * sAlpha[j + 0]; a0.y += v0.y * sAlpha[j + 0];
        a1.x += v1.x * sAlpha[j + 1]; a1.y += v1.y * sAlpha[j + 1];
        a2.x += v2.x * sAlpha[j + 2]; a2.y += v2.y * sAlpha[j + 2];
        a3.x += v3.x * sAlpha[j + 3]; a3.y += v3.y * sAlpha[j + 3];
    }
    for (; j < CH; ++j) {
        const float2 v = *reinterpret_cast<const float2*>(cb + (size_t)j * DD);
        a0.x += v.x * sAlpha[j]; a0.y += v.y * sAlpha[j];
    }
    const float accx = (a0.x + a1.x) + (a2.x + a3.x);
    const float accy = (a0.y + a1.y) + (a2.y + a3.y);
    out[b * DD + d]     = accx * invL;
    out[b * DD + d + 1] = accy * invL;
}

extern "C" void kernel_launch(void* const* d_in, const int* in_sizes, int n_in,
                              void* d_out, int out_size, void* d_ws, size_t ws_size,
                              hipStream_t stream) {
    const float* inp  = (const float*)d_in[0];
    const int*   lens = (const int*)d_in[1];
    const float* slot = (const float*)d_in[2];
    float* out = (float*)d_out;

    // chunks-per-batch; record = (ml float2) + c[512] floats
    int CH = 64;
    while (CH > 1 && (size_t)BB * CH * (2 + DD) * sizeof(float) > ws_size)
        CH >>= 1;
    const int R  = TT / CH;      // rows per chunk
    const int RW = R / 4;        // rows per wave
    const int P  = BB * CH;

    float2* ml_arr = (float2*)d_ws;
    float*  c_arr  = (float*)(ml_arr + P);

    dim3 grid1(CH, BB, 1);
    slot_partial_kernel<<<grid1, 256, 0, stream>>>(inp, lens, slot,
                                                   ml_arr, c_arr,
                                                   CH, R, RW);
    slot_combine_kernel<<<BB, 256, 0, stream>>>(ml_arr, c_arr, out, CH);
}